// Round 17
// baseline (3613.475 us; speedup 1.0000x reference)
//
#include <hip/hip_runtime.h>
#include <stdint.h>

#define NWG 208

typedef __attribute__((ext_vector_type(8))) short short8;
typedef __attribute__((ext_vector_type(4))) float floatx4;
typedef __attribute__((ext_vector_type(4))) unsigned int uintx4;

static constexpr int Bb = 128, Tt = 256, Dl = 256, Hs = 512, Hb = 1024;
static constexpr int D = 32;     // ring depth >> live span
static constexpr int LAG = 4;    // backpressure lag

// ---- fixed workspace header ----
static constexpr size_t OFF_FLAGS = 0;                                   // i32[256]
static constexpr size_t OFF_B1  = 1024;
static constexpr size_t OFF_B2  = OFF_B1 + 2048*4;
static constexpr size_t OFF_B3  = OFF_B2 + 2048*4;
static constexpr size_t OFF_BL  = OFF_B3 + 4096*4;
static constexpr size_t OFF_W1  = OFF_BL + 1024;
static constexpr size_t OFF_W2  = OFF_W1 + (size_t)2048*768*2;
static constexpr size_t OFF_W3  = OFF_W2 + (size_t)2048*1024*2;
static constexpr size_t OFF_WL  = OFF_W3 + (size_t)4096*1536*2;
static constexpr size_t FIXED_END = OFF_WL + (size_t)256*1024*2;
// rings (fragment-blocked, r10-proven layout) + full prestaged X
static constexpr size_t OFF_H1R  = FIXED_END;
static constexpr size_t OFF_H2R  = OFF_H1R + (size_t)D*Bb*Hs*2;
static constexpr size_t OFF_H3R  = OFF_H2R + (size_t)D*Bb*Hs*2;
static constexpr size_t OFF_XALL = OFF_H3R + (size_t)D*Bb*Hb*2;
static constexpr size_t WS_NEED  = OFF_XALL + (size_t)Tt*Bb*Dl*2;   // ~53.4 MB

static constexpr int SMEM_BYTES = 135168;   // 128K weights (+16K reduce inside for L3) + 4K h-staging
static constexpr int RED_OFF    = 98304;    // L3 weights end exactly here (32*1536*2)
static constexpr int STG_OFF    = 131072;

__device__ __forceinline__ unsigned short f2bf(float f) {
  unsigned int u = __float_as_uint(f);
  unsigned int r = (u + 0x7fffu + ((u >> 16) & 1u)) >> 16;
  return (unsigned short)r;
}
__device__ __forceinline__ float sigm(float x) { return 1.f/(1.f + __expf(-x)); }
__device__ __forceinline__ float tanh_f(float x) {
  x = fminf(fmaxf(x, -15.f), 15.f);
  float e = __expf(-2.f*x);
  return (1.f - e)/(1.f + e);
}
__device__ __forceinline__ size_t blk_off(int row, int u) {
  return ((size_t)(u >> 5)*8 + (row >> 4))*512 + (size_t)((u & 31) >> 3)*128
       + (size_t)(row & 15)*8 + (u & 7);
}
__device__ __forceinline__ void st_dword_cg(void* p, unsigned int v) {
  asm volatile("global_store_dword %0, %1, off sc0 sc1" :: "v"(p), "v"(v) : "memory");
}
__device__ __forceinline__ void st_b128_cg(void* p, uintx4 v) {
  asm volatile("global_store_dwordx4 %0, %1, off sc0 sc1" :: "v"(p), "v"(v) : "memory");
}
__device__ __forceinline__ void waitcnt_vm0() {
  asm volatile("s_waitcnt vmcnt(0)" ::: "memory");
}

// group-min flag wait (n multiple of 4): dwordx4 per lane
__device__ __forceinline__ void wait_ge(const unsigned int* f, int n, int tgt, int lane) {
  if (tgt <= 0) return;
  const int nl = n >> 2;
  for (;;) {
    int ok = 1;
    if (lane < nl) {
      uintx4 v;
      asm volatile("global_load_dwordx4 %0, %1, off sc0 sc1\n\ts_waitcnt vmcnt(0)"
                   : "=v"(v) : "v"(f + lane*4) : "memory");
      if ((int)v[0] < tgt || (int)v[1] < tgt || (int)v[2] < tgt || (int)v[3] < tgt) ok = 0;
    }
    if (__all(ok)) return;
    __builtin_amdgcn_s_sleep(2);
  }
}

// ---------------- init ----------------
__global__ void lstm_init(
    const float* __restrict__ X,
    const float* __restrict__ Wih1, const float* __restrict__ Whh1,
    const float* __restrict__ bih1, const float* __restrict__ bhh1,
    const float* __restrict__ Wih2, const float* __restrict__ Whh2,
    const float* __restrict__ bih2, const float* __restrict__ bhh2,
    const float* __restrict__ Wih3, const float* __restrict__ Whh3,
    const float* __restrict__ bih3, const float* __restrict__ bhh3,
    const float* __restrict__ Wlin, const float* __restrict__ blin,
    unsigned char* __restrict__ ws)
{
  size_t i0 = (size_t)blockIdx.x*blockDim.x + threadIdx.x;
  size_t np = (size_t)gridDim.x*blockDim.x;

  unsigned int* fl = (unsigned int*)(ws + OFF_FLAGS);
  for (size_t i = i0; i < 256; i += np) fl[i] = 0u;

  float* b1 = (float*)(ws + OFF_B1);
  float* b2 = (float*)(ws + OFF_B2);
  float* b3 = (float*)(ws + OFF_B3);
  float* bl = (float*)(ws + OFF_BL);
  for (size_t i = i0; i < 2048; i += np) b1[i] = bih1[i] + bhh1[i];
  for (size_t i = i0; i < 2048; i += np) b2[i] = bih2[i] + bhh2[i];
  for (size_t i = i0; i < 4096; i += np) b3[i] = bih3[i] + bhh3[i];
  for (size_t i = i0; i < 256;  i += np) bl[i] = blin[i];

  unsigned short* w1 = (unsigned short*)(ws + OFF_W1);
  unsigned short* w2 = (unsigned short*)(ws + OFF_W2);
  unsigned short* w3 = (unsigned short*)(ws + OFF_W3);
  unsigned short* wl = (unsigned short*)(ws + OFF_WL);
  for (size_t i = i0; i < (size_t)2048*768; i += np) {
    size_t r = i/768, k = i - r*768;
    float v = (k < 256) ? Wih1[r*256 + k] : Whh1[r*512 + (k - 256)];
    w1[i] = f2bf(v);
  }
  for (size_t i = i0; i < (size_t)2048*1024; i += np) {
    size_t r = i >> 10, k = i & 1023;
    float v = (k < 512) ? Wih2[r*512 + k] : Whh2[r*512 + (k - 512)];
    w2[i] = f2bf(v);
  }
  for (size_t i = i0; i < (size_t)4096*1536; i += np) {
    size_t r = i/1536, k = i - r*1536;
    float v = (k < 512) ? Wih3[r*512 + k] : Whh3[r*1024 + (k - 512)];
    w3[i] = f2bf(v);
  }
  for (size_t i = i0; i < (size_t)256*1024; i += np) wl[i] = f2bf(Wlin[i]);

  // zero all h-ring slots
  unsigned short* rings = (unsigned short*)(ws + OFF_H1R);
  const size_t nring = (size_t)D*Bb*Hs + (size_t)D*Bb*Hs + (size_t)D*Bb*Hb;
  for (size_t i = i0; i < nring; i += np) rings[i] = 0;

  // prestage ALL X as bf16, blocked layout, one 64KB slot per t
  unsigned short* xall = (unsigned short*)(ws + OFF_XALL);
  for (size_t i = i0; i < (size_t)Tt*Bb*Dl; i += np) {
    size_t t = i >> 15, rem = i & 32767;
    size_t b = rem >> 8, d = rem & 255;
    xall[t*32768 + blk_off((int)b, (int)d)] = f2bf(X[(b*(size_t)Tt + t)*Dl + d]);
  }
}

// ---------------- per-layer step ----------------
// TYPE0 (L1): K=768, KB1=256, MF=2, waves=(m4 x n2)        ; no K-split
// TYPE1 (L2): K=1024, KB1=512, MF=2, waves=(m4 x n2)       ; no K-split
// TYPE2 (L3): K=1536, KB1=512, MF=2, waves=(m4 x ksplit2)  ; LDS pair-reduce
template<int TYPE>
__device__ __forceinline__ void layer_phase(
    const unsigned short* __restrict__ segA,
    const unsigned short* __restrict__ segB,
    unsigned short* __restrict__ hout,
    unsigned char* __restrict__ smem,
    const float* __restrict__ bias_r,
    float (&creg)[2][2][4],
    int U0, int wv, int lane, int tid)
{
  constexpr int K    = (TYPE==0 ? 768 : TYPE==1 ? 1024 : 1536);
  constexpr int KB1  = (TYPE==0 ? 256 : 512);
  constexpr int MF   = 2;
  constexpr int CKS  = 4;
  constexpr bool KS2 = (TYPE==2);
  constexpr int KSPAN = KS2 ? (K/2) : K;      // per-wave K coverage
  constexpr int NCH  = KSPAN/(32*CKS);        // L1:6  L2:8  L3:6
  const int l15 = lane & 15;
  const int g   = l15 >> 2;
  const int mbase = (wv & 3)*32;
  const int kq    = KS2 ? (wv >> 2) : 0;
  const int nfb   = KS2 ? 0 : (wv >> 2)*2;
  const int k0    = kq * KSPAN;

  const size_t lof = (size_t)(lane >> 4)*128 + (size_t)l15*8;
  const unsigned short* pa[MF];
  const unsigned short* pb[MF];
  #pragma unroll
  for (int mf = 0; mf < MF; ++mf) {
    const size_t rb = (size_t)((mbase >> 4) + mf)*512;
    pa[mf] = segA + rb + lof;
    pb[mf] = segB + rb + lof;
  }
  int rowbyte[2], xr[2];
  #pragma unroll
  for (int nf = 0; nf < 2; ++nf) {
    const int rp = (nfb + nf)*16 + l15;
    rowbyte[nf] = rp*(K*2);
    xr[nf] = (rp & 7) << 4;
  }
  const int klobyte = ((lane >> 4) << 3)*2;

  floatx4 acc[MF][2];
  #pragma unroll
  for (int mf = 0; mf < MF; ++mf)
    #pragma unroll
    for (int nf = 0; nf < 2; ++nf) {
      float bv = (KS2 && kq == 1) ? 0.f : bias_r[nf];   // K-split: bias only in kq=0 partial
      floatx4 b4 = {bv, bv, bv, bv};
      acc[mf][nf] = b4;
    }

  short8 B0[CKS][MF], B1[CKS][MF], B2[CKS][MF];
  auto LOADC = [&](int c, short8 (&A)[CKS][MF]) {
    #pragma unroll
    for (int ks = 0; ks < CKS; ++ks) {
      const int kb = k0 + (c*CKS + ks)*32;
      #pragma unroll
      for (int mf = 0; mf < MF; ++mf) {
        const unsigned short* p = (kb < KB1)
            ? pa[mf] + (size_t)(kb >> 5)*4096
            : pb[mf] + (size_t)((kb - KB1) >> 5)*4096;
        A[ks][mf] = *(const short8*)p;
      }
    }
  };
  auto MM = [&](int c, short8 (&A)[CKS][MF]) {
    #pragma unroll
    for (int ks = 0; ks < CKS; ++ks) {
      const int kb = k0 + (c*CKS + ks)*32;
      short8 bf[2];
      #pragma unroll
      for (int nf = 0; nf < 2; ++nf)
        bf[nf] = *(const short8*)(smem + rowbyte[nf] + ((kb*2 + klobyte) ^ xr[nf]));
      #pragma unroll
      for (int mf = 0; mf < MF; ++mf)
        #pragma unroll
        for (int nf = 0; nf < 2; ++nf)
          acc[mf][nf] = __builtin_amdgcn_mfma_f32_16x16x32_bf16(A[ks][mf], bf[nf], acc[mf][nf], 0, 0, 0);
    }
  };
  auto LOADB = [&](int c, int b) { if (b == 0) LOADC(c, B0); else if (b == 1) LOADC(c, B1); else LOADC(c, B2); };
  auto MMB   = [&](int c, int b) { if (b == 0) MM(c, B0);    else if (b == 1) MM(c, B1);    else MM(c, B2); };

  LOADB(0, 0); LOADB(1, 1); LOADB(2, 2);
  #pragma unroll
  for (int ch = 0; ch < NCH; ++ch) {     // fully unrolled; static buffer indices
    MMB(ch, ch % 3);
    if (ch + 3 < NCH) LOADB(ch + 3, ch % 3);
  }

  // ---- K-split pair-reduce (L3 only): kq=1 waves dump partials, kq=0 adds ----
  if (KS2) {
    floatx4* red = (floatx4*)(smem + RED_OFF);
    __syncthreads();
    if (kq == 1) {
      #pragma unroll
      for (int mf = 0; mf < MF; ++mf)
        #pragma unroll
        for (int nf = 0; nf < 2; ++nf)
          red[(((wv & 3)*4 + mf*2 + nf) << 6) + lane] = acc[mf][nf];
    }
    __syncthreads();
    if (kq == 0) {
      #pragma unroll
      for (int mf = 0; mf < MF; ++mf)
        #pragma unroll
        for (int nf = 0; nf < 2; ++nf)
          acc[mf][nf] += red[(((wv & 3)*4 + mf*2 + nf) << 6) + lane];
    }
  }

  // ---- cell update -> LDS staging (kq=0 waves only for L3; all waves otherwise) ----
  unsigned short* stg = (unsigned short*)(smem + STG_OFF);
  const int a = (U0 & 31) >> 3;
  if (!KS2 || kq == 0) {
    #pragma unroll
    for (int nf = 0; nf < 2; ++nf) {
      const int u = U0 + (nfb + nf)*4 + (l15 & 3);
      #pragma unroll
      for (int mf = 0; mf < MF; ++mf) {
        float h4[4];
        #pragma unroll
        for (int j = 0; j < 4; ++j) {
          float s0  = acc[mf][nf][j];
          float s4  = __shfl_xor(s0, 4);
          float s8  = __shfl_xor(s0, 8);
          float s12 = __shfl_xor(s0, 12);
          float iv = (g==0)?s0 :(g==1)?s4 :(g==2)?s8 :s12;
          float fv = (g==0)?s4 :(g==1)?s0 :(g==2)?s12:s8;
          float gv = (g==0)?s8 :(g==1)?s12:(g==2)?s0 :s4;
          float ov = (g==0)?s12:(g==1)?s8 :(g==2)?s4 :s0;
          float c  = sigm(fv)*creg[mf][nf][j] + sigm(iv)*tanh_f(gv);
          creg[mf][nf][j] = c;
          h4[j] = sigm(ov)*tanh_f(c);
        }
        float hs = (g==0)?h4[0]:(g==1)?h4[1]:(g==2)?h4[2]:h4[3];
        const int row = mbase + mf*16 + ((lane >> 4) << 2) + g;
        const int c2  = (TYPE==2) ? (row >> 4)
                                  : ((row >> 4)*2 + (((u & 31) >> 3) - a));
        stg[c2*128 + (row & 15)*8 + (u & 7)] = f2bf(hs);
      }
    }
  }
  __syncthreads();

  const size_t gbase = (size_t)(U0 >> 5)*4096;
  if (TYPE == 2) {
    if (tid < 128) {
      const int c2 = tid >> 4, w = tid & 15;
      short8 v = *(const short8*)(stg + c2*128 + w*8);
      st_b128_cg(hout + gbase + (size_t)c2*512 + (size_t)a*128 + w*8, *(uintx4*)&v);
    }
  } else {
    if (tid < 256) {
      const int c2 = tid >> 4, w = tid & 15;
      short8 v = *(const short8*)(stg + c2*128 + w*8);
      st_b128_cg(hout + gbase + (size_t)(c2 >> 1)*512 + (size_t)(a + (c2 & 1))*128 + w*8, *(uintx4*)&v);
    }
  }
}

// ---------------- persistent dataflow kernel (512 threads, no global barrier) ----------------
// wg 0..31: L1 | 32..63: L2 | 64..191: L3 | 192..207: head
__global__ void __launch_bounds__(512, 2)
lstm_persist(float* __restrict__ out, unsigned char* __restrict__ ws)
{
  extern __shared__ unsigned char smem[];

  __builtin_amdgcn_fence(__ATOMIC_ACQUIRE, "agent");  // clear pre-dispatch stale lines once

  const int tid  = threadIdx.x;
  const int lane = tid & 63;
  const int wv   = tid >> 6;
  const int wg   = blockIdx.x;
  const int l15  = lane & 15;

  unsigned int* flags = (unsigned int*)(ws + OFF_FLAGS);
  const float* bias1 = (const float*)(ws + OFF_B1);
  const float* bias2 = (const float*)(ws + OFF_B2);
  const float* bias3 = (const float*)(ws + OFF_B3);
  const float* biasl = (const float*)(ws + OFF_BL);
  const unsigned short* W1 = (const unsigned short*)(ws + OFF_W1);
  const unsigned short* W2 = (const unsigned short*)(ws + OFF_W2);
  const unsigned short* W3 = (const unsigned short*)(ws + OFF_W3);
  const unsigned short* WL = (const unsigned short*)(ws + OFF_WL);
  unsigned short* h1r = (unsigned short*)(ws + OFF_H1R);
  unsigned short* h2r = (unsigned short*)(ws + OFF_H2R);
  unsigned short* h3r = (unsigned short*)(ws + OFF_H3R);
  unsigned short* Xall = (unsigned short*)(ws + OFF_XALL);

  auto slot = [](int t) -> size_t { return (size_t)(t & (D - 1)); };
  const size_t HSs = (size_t)Bb*Hs, HBs = (size_t)Bb*Hb, XBs = (size_t)Bb*Dl;

  // role decode
  int type, U0 = 0, osec = 0, K = 0, WROWS = 0, HGATE = 0;
  const unsigned short* Wg = nullptr; const float* biasp = nullptr;
  if (wg < 32)        { type = 0; U0 = wg*16;        Wg = W1; biasp = bias1; K = 768;  WROWS = 64; HGATE = 512; }
  else if (wg < 64)   { type = 1; U0 = (wg-32)*16;   Wg = W2; biasp = bias2; K = 1024; WROWS = 64; HGATE = 512; }
  else if (wg < 192)  { type = 2; U0 = (wg-64)*8;    Wg = W3; biasp = bias3; K = 1536; WROWS = 32; HGATE = 1024; }
  else                { type = 3; osec = (wg-192)*16; Wg = WL; K = 1024; WROWS = 16; }

  // prologue: weight slice -> LDS (packed rows: quad=4 units x 4 gates), XOR-swizzled
  {
    const int rowchunks = K >> 3;
    for (int idx = tid; idx < WROWS*rowchunks; idx += 512) {
      const int rp = idx / rowchunks, kc = idx - rp*rowchunks;
      int R;
      if (type == 3) R = osec + rp;
      else {
        const int c = rp & 15;
        R = (c >> 2)*HGATE + U0 + (rp >> 4)*4 + (c & 3);
      }
      uintx4 v = *(const uintx4*)(Wg + (size_t)R*K + kc*8);
      const int db = rp*(K*2) + ((kc*16) ^ ((rp & 7) << 4));
      *(uintx4*)(smem + db) = v;
    }
  }

  float bias_r[2] = {0.f, 0.f};
  if (type < 3) {
    const int g   = l15 >> 2;
    const int nfb = (type == 2 ? 0 : (wv >> 2)*2);
    #pragma unroll
    for (int nf = 0; nf < 2; ++nf) {
      const int u = U0 + (nfb + nf)*4 + (l15 & 3);
      bias_r[nf] = biasp[g*HGATE + u];
    }
  } else {
    bias_r[0] = biasl[osec + l15];
  }

  float creg[2][2][4];
  #pragma unroll
  for (int a = 0; a < 2; ++a)
    #pragma unroll
    for (int b = 0; b < 2; ++b)
      #pragma unroll
      for (int c = 0; c < 4; ++c) creg[a][b][c] = 0.f;

  __syncthreads();

  for (int t = 0; t < Tt; ++t) {
    // ---- dependency waits: each group polled by a DIFFERENT wave, concurrently ----
    if (type == 0) {
      if (wv == 0)      wait_ge(flags + 0, 32, t, lane);
      else if (wv == 1) wait_ge(flags + 32, 32, t - LAG, lane);
    } else if (type == 1) {
      if (wv == 0)      wait_ge(flags + 0, 32, t + 1, lane);
      else if (wv == 1) wait_ge(flags + 32, 32, t, lane);
      else if (wv == 2) wait_ge(flags + 64, 128, t - LAG, lane);
    } else if (type == 2) {
      if (wv == 0)      wait_ge(flags + 32, 32, t + 1, lane);
      else if (wv == 1) wait_ge(flags + 64, 128, t, lane);
      else if (wv == 2) wait_ge(flags + 192, 16, t - LAG, lane);
    } else {
      if (wv == 0)      wait_ge(flags + 64, 128, t + 1, lane);
    }
    __syncthreads();

    // ---- compute step t ----
    if (type == 0) {
      layer_phase<0>(Xall + (size_t)t*XBs,
                     h1r + slot(t-1)*HSs,
                     h1r + slot(t)*HSs,
                     smem, bias_r, creg, U0, wv, lane, tid);
    } else if (type == 1) {
      layer_phase<1>(h1r + slot(t)*HSs,
                     h2r + slot(t-1)*HSs,
                     h2r + slot(t)*HSs,
                     smem, bias_r, creg, U0, wv, lane, tid);
    } else if (type == 2) {
      layer_phase<2>(h2r + slot(t)*HSs,
                     h3r + slot(t-1)*HBs,
                     h3r + slot(t)*HBs,
                     smem, bias_r, creg, U0, wv, lane, tid);
    } else {
      // ---- linear head step t: per WG m128 x n16, 8 waves x 16 rows ----
      const unsigned short* hA = h3r + slot(t)*HBs;
      const size_t lof = (size_t)(lane >> 4)*128 + (size_t)l15*8;
      const unsigned short* pa0 = hA + (size_t)wv*512 + lof;
      const int rowbyte = l15*2048;
      const int xr = (l15 & 7) << 4;
      const int klobyte = ((lane >> 4) << 3)*2;
      floatx4 oacc;
      { floatx4 b4 = {bias_r[0], bias_r[0], bias_r[0], bias_r[0]}; oacc = b4; }
      short8 A0[4], A1[4];
      auto HLOAD = [&](int c, short8 (&A)[4]) {
        #pragma unroll
        for (int ks = 0; ks < 4; ++ks)
          A[ks] = *(const short8*)(pa0 + (size_t)(c*4 + ks)*4096);
      };
      auto HMM = [&](int c, short8 (&A)[4]) {
        #pragma unroll
        for (int ks = 0; ks < 4; ++ks) {
          const int kb = c*128 + ks*32;
          short8 bw = *(const short8*)(smem + rowbyte + ((kb*2 + klobyte) ^ xr));
          oacc = __builtin_amdgcn_mfma_f32_16x16x32_bf16(A[ks], bw, oacc, 0, 0, 0);
        }
      };
      HLOAD(0, A0);
      #pragma unroll 1
      for (int ch = 0; ch < 8; ch += 2) {
        HLOAD(ch + 1, A1);
        HMM(ch, A0);
        if (ch + 2 < 8) HLOAD(ch + 2, A0);
        HMM(ch + 1, A1);
      }
      const int col = osec + l15;
      const int b0 = wv*16 + ((lane >> 4) << 2);
      #pragma unroll
      for (int j = 0; j < 4; ++j)
        st_dword_cg(out + ((size_t)t*Bb + b0 + j)*Dl + col,
                    __float_as_uint(oacc[j]));
    }

    // ---- completion publish + periodic local cache invalidate ----
    waitcnt_vm0();
    __syncthreads();
    if (tid == 0) st_dword_cg(flags + wg, (unsigned)(t + 1));
    if ((t & 7) == 7)
      __builtin_amdgcn_fence(__ATOMIC_ACQUIRE, "agent");
  }
}

extern "C" void kernel_launch(void* const* d_in, const int* in_sizes, int n_in,
                              void* d_out, int out_size, void* d_ws, size_t ws_size,
                              hipStream_t stream)
{
  if (ws_size < WS_NEED) return;

  const float* X    = (const float*)d_in[0];
  const float* Wih1 = (const float*)d_in[1];
  const float* Whh1 = (const float*)d_in[2];
  const float* bih1 = (const float*)d_in[3];
  const float* bhh1 = (const float*)d_in[4];
  const float* Wih2 = (const float*)d_in[5];
  const float* Whh2 = (const float*)d_in[6];
  const float* bih2 = (const float*)d_in[7];
  const float* bhh2 = (const float*)d_in[8];
  const float* Wih3 = (const float*)d_in[9];
  const float* Whh3 = (const float*)d_in[10];
  const float* bih3 = (const float*)d_in[11];
  const float* bhh3 = (const float*)d_in[12];
  const float* Wlin = (const float*)d_in[13];
  const float* blin = (const float*)d_in[14];
  unsigned char* ws = (unsigned char*)d_ws;

  lstm_init<<<2048, 256, 0, stream>>>(X, Wih1, Whh1, bih1, bhh1,
                                      Wih2, Whh2, bih2, bhh2,
                                      Wih3, Whh3, bih3, bhh3,
                                      Wlin, blin, ws);
  lstm_persist<<<NWG, 512, SMEM_BYTES, stream>>>((float*)d_out, ws);
}

// Round 18
// 3353.738 us; speedup vs baseline: 1.0774x; 1.0774x over previous
//
#include <hip/hip_runtime.h>
#include <stdint.h>

#define NWG 208

typedef __attribute__((ext_vector_type(8))) short short8;
typedef __attribute__((ext_vector_type(4))) float floatx4;
typedef __attribute__((ext_vector_type(4))) unsigned int uintx4;

static constexpr int Bb = 128, Tt = 256, Dl = 256, Hs = 512, Hb = 1024;
static constexpr int D = 32;     // ring depth >> live span
static constexpr int LAG = 4;    // backpressure lag

// ---- fixed workspace header ----
static constexpr size_t OFF_FLAGS = 0;                                   // i32[256]
static constexpr size_t OFF_B1  = 1024;
static constexpr size_t OFF_B2  = OFF_B1 + 2048*4;
static constexpr size_t OFF_B3  = OFF_B2 + 2048*4;
static constexpr size_t OFF_BL  = OFF_B3 + 4096*4;
static constexpr size_t OFF_W1  = OFF_BL + 1024;
static constexpr size_t OFF_W2  = OFF_W1 + (size_t)2048*768*2;
static constexpr size_t OFF_W3  = OFF_W2 + (size_t)2048*1024*2;
static constexpr size_t OFF_WL  = OFF_W3 + (size_t)4096*1536*2;
static constexpr size_t FIXED_END = OFF_WL + (size_t)256*1024*2;
// rings (fragment-blocked, r10-proven layout) + full prestaged X
static constexpr size_t OFF_H1R  = FIXED_END;
static constexpr size_t OFF_H2R  = OFF_H1R + (size_t)D*Bb*Hs*2;
static constexpr size_t OFF_H3R  = OFF_H2R + (size_t)D*Bb*Hs*2;
static constexpr size_t OFF_XALL = OFF_H3R + (size_t)D*Bb*Hb*2;
static constexpr size_t WS_NEED  = OFF_XALL + (size_t)Tt*Bb*Dl*2;   // ~53.4 MB

static constexpr int SMEM_BYTES = 135168;   // 128K weights + 4K h-staging
static constexpr int STG_OFF    = 131072;

__device__ __forceinline__ unsigned short f2bf(float f) {
  unsigned int u = __float_as_uint(f);
  unsigned int r = (u + 0x7fffu + ((u >> 16) & 1u)) >> 16;
  return (unsigned short)r;
}
__device__ __forceinline__ float sigm(float x) { return 1.f/(1.f + __expf(-x)); }
__device__ __forceinline__ float tanh_f(float x) {
  x = fminf(fmaxf(x, -15.f), 15.f);
  float e = __expf(-2.f*x);
  return (1.f - e)/(1.f + e);
}
__device__ __forceinline__ size_t blk_off(int row, int u) {
  return ((size_t)(u >> 5)*8 + (row >> 4))*512 + (size_t)((u & 31) >> 3)*128
       + (size_t)(row & 15)*8 + (u & 7);
}
__device__ __forceinline__ void st_dword_cg(void* p, unsigned int v) {
  asm volatile("global_store_dword %0, %1, off sc0 sc1" :: "v"(p), "v"(v) : "memory");
}
__device__ __forceinline__ void st_b128_cg(void* p, uintx4 v) {
  asm volatile("global_store_dwordx4 %0, %1, off sc0 sc1" :: "v"(p), "v"(v) : "memory");
}
__device__ __forceinline__ void waitcnt_vm0() {
  asm volatile("s_waitcnt vmcnt(0)" ::: "memory");
}

// group-min flag wait: spin until flags[base..base+n) all >= tgt (signed; tgt<=0 -> no-op)
// n must be a multiple of 4 (all groups are): dwordx4 per lane.
__device__ __forceinline__ void wait_ge(const unsigned int* f, int n, int tgt, int lane) {
  if (tgt <= 0) return;
  const int nl = n >> 2;
  for (;;) {
    int ok = 1;
    if (lane < nl) {
      uintx4 v;
      asm volatile("global_load_dwordx4 %0, %1, off sc0 sc1\n\ts_waitcnt vmcnt(0)"
                   : "=v"(v) : "v"(f + lane*4) : "memory");
      if ((int)v[0] < tgt || (int)v[1] < tgt || (int)v[2] < tgt || (int)v[3] < tgt) ok = 0;
    }
    if (__all(ok)) return;
    __builtin_amdgcn_s_sleep(2);
  }
}

// ---------------- init ----------------
__global__ void lstm_init(
    const float* __restrict__ X,
    const float* __restrict__ Wih1, const float* __restrict__ Whh1,
    const float* __restrict__ bih1, const float* __restrict__ bhh1,
    const float* __restrict__ Wih2, const float* __restrict__ Whh2,
    const float* __restrict__ bih2, const float* __restrict__ bhh2,
    const float* __restrict__ Wih3, const float* __restrict__ Whh3,
    const float* __restrict__ bih3, const float* __restrict__ bhh3,
    const float* __restrict__ Wlin, const float* __restrict__ blin,
    unsigned char* __restrict__ ws)
{
  size_t i0 = (size_t)blockIdx.x*blockDim.x + threadIdx.x;
  size_t np = (size_t)gridDim.x*blockDim.x;

  unsigned int* fl = (unsigned int*)(ws + OFF_FLAGS);
  for (size_t i = i0; i < 256; i += np) fl[i] = 0u;

  float* b1 = (float*)(ws + OFF_B1);
  float* b2 = (float*)(ws + OFF_B2);
  float* b3 = (float*)(ws + OFF_B3);
  float* bl = (float*)(ws + OFF_BL);
  for (size_t i = i0; i < 2048; i += np) b1[i] = bih1[i] + bhh1[i];
  for (size_t i = i0; i < 2048; i += np) b2[i] = bih2[i] + bhh2[i];
  for (size_t i = i0; i < 4096; i += np) b3[i] = bih3[i] + bhh3[i];
  for (size_t i = i0; i < 256;  i += np) bl[i] = blin[i];

  unsigned short* w1 = (unsigned short*)(ws + OFF_W1);
  unsigned short* w2 = (unsigned short*)(ws + OFF_W2);
  unsigned short* w3 = (unsigned short*)(ws + OFF_W3);
  unsigned short* wl = (unsigned short*)(ws + OFF_WL);
  for (size_t i = i0; i < (size_t)2048*768; i += np) {
    size_t r = i/768, k = i - r*768;
    float v = (k < 256) ? Wih1[r*256 + k] : Whh1[r*512 + (k - 256)];
    w1[i] = f2bf(v);
  }
  for (size_t i = i0; i < (size_t)2048*1024; i += np) {
    size_t r = i >> 10, k = i & 1023;
    float v = (k < 512) ? Wih2[r*512 + k] : Whh2[r*512 + (k - 512)];
    w2[i] = f2bf(v);
  }
  for (size_t i = i0; i < (size_t)4096*1536; i += np) {
    size_t r = i/1536, k = i - r*1536;
    float v = (k < 512) ? Wih3[r*512 + k] : Whh3[r*1024 + (k - 512)];
    w3[i] = f2bf(v);
  }
  for (size_t i = i0; i < (size_t)256*1024; i += np) wl[i] = f2bf(Wlin[i]);

  // zero all h-ring slots
  unsigned short* rings = (unsigned short*)(ws + OFF_H1R);
  const size_t nring = (size_t)D*Bb*Hs + (size_t)D*Bb*Hs + (size_t)D*Bb*Hb;
  for (size_t i = i0; i < nring; i += np) rings[i] = 0;

  // prestage ALL X as bf16, blocked layout, one 64KB slot per t
  unsigned short* xall = (unsigned short*)(ws + OFF_XALL);
  for (size_t i = i0; i < (size_t)Tt*Bb*Dl; i += np) {
    size_t t = i >> 15, rem = i & 32767;
    size_t b = rem >> 8, d = rem & 255;
    xall[t*32768 + blk_off((int)b, (int)d)] = f2bf(X[(b*(size_t)Tt + t)*Dl + d]);
  }
}

// ---------------- per-layer step: 3-buffer static pipeline + LDS-staged coalesced store ----------------
template<int TYPE>
__device__ __forceinline__ void layer_phase(
    const unsigned short* __restrict__ segA,
    const unsigned short* __restrict__ segB,
    unsigned short* __restrict__ hout,
    unsigned char* __restrict__ smem,
    const float* __restrict__ bias_r,
    float (&creg)[2][2][4],
    int U0, int wv, int lane, int tid)
{
  constexpr int K    = (TYPE==0 ? 768 : TYPE==1 ? 1024 : 1536);
  constexpr int KB1  = (TYPE==0 ? 256 : 512);
  constexpr int MF   = (TYPE==2 ? 1 : 2);
  constexpr int CKS  = (TYPE==2 ? 8 : 4);
  constexpr int NCH  = K/(32*CKS);          // L1:6  L2:8  L3:6
  const int l15 = lane & 15;
  const int g   = l15 >> 2;
  const int mbase = (TYPE==2 ? wv*16 : (wv&3)*32);
  const int nfb   = (TYPE==2 ? 0 : (wv>>2)*2);

  const size_t lof = (size_t)(lane >> 4)*128 + (size_t)l15*8;
  const unsigned short* pa[MF];
  const unsigned short* pb[MF];
  #pragma unroll
  for (int mf = 0; mf < MF; ++mf) {
    const size_t rb = (size_t)((mbase >> 4) + mf)*512;
    pa[mf] = segA + rb + lof;
    pb[mf] = segB + rb + lof;
  }
  int rowbyte[2], xr[2];
  #pragma unroll
  for (int nf = 0; nf < 2; ++nf) {
    const int rp = (nfb + nf)*16 + l15;
    rowbyte[nf] = rp*(K*2);
    xr[nf] = (rp & 7) << 4;
  }
  const int klobyte = ((lane >> 4) << 3)*2;

  floatx4 acc[MF][2];
  #pragma unroll
  for (int mf = 0; mf < MF; ++mf)
    #pragma unroll
    for (int nf = 0; nf < 2; ++nf) {
      float bv = bias_r[nf];
      floatx4 b4 = {bv, bv, bv, bv};
      acc[mf][nf] = b4;
    }

  short8 B0[CKS][MF], B1[CKS][MF], B2[CKS][MF];
  auto LOADC = [&](int c, short8 (&A)[CKS][MF]) {
    #pragma unroll
    for (int ks = 0; ks < CKS; ++ks) {
      const int kb = (c*CKS + ks)*32;
      #pragma unroll
      for (int mf = 0; mf < MF; ++mf) {
        const unsigned short* p = (kb < KB1)
            ? pa[mf] + (size_t)(kb >> 5)*4096
            : pb[mf] + (size_t)((kb - KB1) >> 5)*4096;
        A[ks][mf] = *(const short8*)p;
      }
    }
  };
  auto MM = [&](int c, short8 (&A)[CKS][MF]) {
    #pragma unroll
    for (int ks = 0; ks < CKS; ++ks) {
      const int kb = (c*CKS + ks)*32;
      short8 bf[2];
      #pragma unroll
      for (int nf = 0; nf < 2; ++nf)
        bf[nf] = *(const short8*)(smem + rowbyte[nf] + ((kb*2 + klobyte) ^ xr[nf]));
      #pragma unroll
      for (int mf = 0; mf < MF; ++mf)
        #pragma unroll
        for (int nf = 0; nf < 2; ++nf)
          acc[mf][nf] = __builtin_amdgcn_mfma_f32_16x16x32_bf16(A[ks][mf], bf[nf], acc[mf][nf], 0, 0, 0);
    }
  };
  auto LOADB = [&](int c, int b) { if (b == 0) LOADC(c, B0); else if (b == 1) LOADC(c, B1); else LOADC(c, B2); };
  auto MMB   = [&](int c, int b) { if (b == 0) MM(c, B0);    else if (b == 1) MM(c, B1);    else MM(c, B2); };

  LOADB(0, 0); LOADB(1, 1); LOADB(2, 2);
  #pragma unroll
  for (int ch = 0; ch < NCH; ++ch) {     // fully unrolled -> all buffer indices static
    MMB(ch, ch % 3);
    if (ch + 3 < NCH) LOADB(ch + 3, ch % 3);
  }

  unsigned short* stg = (unsigned short*)(smem + STG_OFF);
  const int a = (U0 & 31) >> 3;
  #pragma unroll
  for (int nf = 0; nf < 2; ++nf) {
    const int u = U0 + (nfb + nf)*4 + (l15 & 3);
    #pragma unroll
    for (int mf = 0; mf < MF; ++mf) {
      float h4[4];
      #pragma unroll
      for (int j = 0; j < 4; ++j) {
        float s0  = acc[mf][nf][j];
        float s4  = __shfl_xor(s0, 4);
        float s8  = __shfl_xor(s0, 8);
        float s12 = __shfl_xor(s0, 12);
        float iv = (g==0)?s0 :(g==1)?s4 :(g==2)?s8 :s12;
        float fv = (g==0)?s4 :(g==1)?s0 :(g==2)?s12:s8;
        float gv = (g==0)?s8 :(g==1)?s12:(g==2)?s0 :s4;
        float ov = (g==0)?s12:(g==1)?s8 :(g==2)?s4 :s0;
        float c  = sigm(fv)*creg[mf][nf][j] + sigm(iv)*tanh_f(gv);
        creg[mf][nf][j] = c;
        h4[j] = sigm(ov)*tanh_f(c);
      }
      float hs = (g==0)?h4[0]:(g==1)?h4[1]:(g==2)?h4[2]:h4[3];
      const int row = mbase + mf*16 + ((lane >> 4) << 2) + g;
      const int c2  = (TYPE==2) ? (row >> 4)
                                : ((row >> 4)*2 + (((u & 31) >> 3) - a));
      stg[c2*128 + (row & 15)*8 + (u & 7)] = f2bf(hs);
    }
  }
  __syncthreads();

  const size_t gbase = (size_t)(U0 >> 5)*4096;
  if (TYPE == 2) {
    if (tid < 128) {
      const int c2 = tid >> 4, w = tid & 15;
      short8 v = *(const short8*)(stg + c2*128 + w*8);
      st_b128_cg(hout + gbase + (size_t)c2*512 + (size_t)a*128 + w*8, *(uintx4*)&v);
    }
  } else {
    if (tid < 256) {
      const int c2 = tid >> 4, w = tid & 15;
      short8 v = *(const short8*)(stg + c2*128 + w*8);
      st_b128_cg(hout + gbase + (size_t)(c2 >> 1)*512 + (size_t)(a + (c2 & 1))*128 + w*8, *(uintx4*)&v);
    }
  }
}

// ---------------- persistent dataflow kernel (512 threads, no global barrier) ----------------
// wg 0..31: L1 | 32..63: L2 | 64..191: L3 | 192..207: head
__global__ void __launch_bounds__(512, 2)
lstm_persist(float* __restrict__ out, unsigned char* __restrict__ ws)
{
  extern __shared__ unsigned char smem[];

  __builtin_amdgcn_fence(__ATOMIC_ACQUIRE, "agent");  // clear pre-dispatch stale lines once

  const int tid  = threadIdx.x;
  const int lane = tid & 63;
  const int wv   = tid >> 6;
  const int wg   = blockIdx.x;
  const int l15  = lane & 15;

  unsigned int* flags = (unsigned int*)(ws + OFF_FLAGS);
  const float* bias1 = (const float*)(ws + OFF_B1);
  const float* bias2 = (const float*)(ws + OFF_B2);
  const float* bias3 = (const float*)(ws + OFF_B3);
  const float* biasl = (const float*)(ws + OFF_BL);
  const unsigned short* W1 = (const unsigned short*)(ws + OFF_W1);
  const unsigned short* W2 = (const unsigned short*)(ws + OFF_W2);
  const unsigned short* W3 = (const unsigned short*)(ws + OFF_W3);
  const unsigned short* WL = (const unsigned short*)(ws + OFF_WL);
  unsigned short* h1r = (unsigned short*)(ws + OFF_H1R);
  unsigned short* h2r = (unsigned short*)(ws + OFF_H2R);
  unsigned short* h3r = (unsigned short*)(ws + OFF_H3R);
  unsigned short* Xall = (unsigned short*)(ws + OFF_XALL);

  auto slot = [](int t) -> size_t { return (size_t)(t & (D - 1)); };
  const size_t HSs = (size_t)Bb*Hs, HBs = (size_t)Bb*Hb, XBs = (size_t)Bb*Dl;

  // role decode
  int type, U0 = 0, osec = 0, K = 0, WROWS = 0, HGATE = 0;
  const unsigned short* Wg = nullptr; const float* biasp = nullptr;
  if (wg < 32)        { type = 0; U0 = wg*16;        Wg = W1; biasp = bias1; K = 768;  WROWS = 64; HGATE = 512; }
  else if (wg < 64)   { type = 1; U0 = (wg-32)*16;   Wg = W2; biasp = bias2; K = 1024; WROWS = 64; HGATE = 512; }
  else if (wg < 192)  { type = 2; U0 = (wg-64)*8;    Wg = W3; biasp = bias3; K = 1536; WROWS = 32; HGATE = 1024; }
  else                { type = 3; osec = (wg-192)*16; Wg = WL; K = 1024; WROWS = 16; }

  // prologue: weight slice -> LDS (packed rows: quad=4 units x 4 gates), XOR-swizzled
  {
    const int rowchunks = K >> 3;
    for (int idx = tid; idx < WROWS*rowchunks; idx += 512) {
      const int rp = idx / rowchunks, kc = idx - rp*rowchunks;
      int R;
      if (type == 3) R = osec + rp;
      else {
        const int c = rp & 15;
        R = (c >> 2)*HGATE + U0 + (rp >> 4)*4 + (c & 3);
      }
      uintx4 v = *(const uintx4*)(Wg + (size_t)R*K + kc*8);
      const int db = rp*(K*2) + ((kc*16) ^ ((rp & 7) << 4));
      *(uintx4*)(smem + db) = v;
    }
  }

  float bias_r[2] = {0.f, 0.f};
  if (type < 3) {
    const int g   = l15 >> 2;
    const int nfb = (type == 2 ? 0 : (wv >> 2)*2);
    #pragma unroll
    for (int nf = 0; nf < 2; ++nf) {
      const int u = U0 + (nfb + nf)*4 + (l15 & 3);
      bias_r[nf] = biasp[g*HGATE + u];
    }
  } else {
    bias_r[0] = biasl[osec + l15];
  }

  float creg[2][2][4];
  #pragma unroll
  for (int a = 0; a < 2; ++a)
    #pragma unroll
    for (int b = 0; b < 2; ++b)
      #pragma unroll
      for (int c = 0; c < 4; ++c) creg[a][b][c] = 0.f;

  __syncthreads();

  for (int t = 0; t < Tt; ++t) {
    // ---- dependency waits: each group polled by a DIFFERENT wave, concurrently ----
    if (type == 0) {
      if (wv == 0)      wait_ge(flags + 0, 32, t, lane);
      else if (wv == 1) wait_ge(flags + 32, 32, t - LAG, lane);
    } else if (type == 1) {
      if (wv == 0)      wait_ge(flags + 0, 32, t + 1, lane);
      else if (wv == 1) wait_ge(flags + 32, 32, t, lane);
      else if (wv == 2) wait_ge(flags + 64, 128, t - LAG, lane);
    } else if (type == 2) {
      if (wv == 0)      wait_ge(flags + 32, 32, t + 1, lane);
      else if (wv == 1) wait_ge(flags + 64, 128, t, lane);
      else if (wv == 2) wait_ge(flags + 192, 16, t - LAG, lane);
    } else {
      if (wv == 0)      wait_ge(flags + 64, 128, t + 1, lane);
    }
    __syncthreads();

    // ---- compute step t ----
    if (type == 0) {
      layer_phase<0>(Xall + (size_t)t*XBs,
                     h1r + slot(t-1)*HSs,
                     h1r + slot(t)*HSs,
                     smem, bias_r, creg, U0, wv, lane, tid);
    } else if (type == 1) {
      layer_phase<1>(h1r + slot(t)*HSs,
                     h2r + slot(t-1)*HSs,
                     h2r + slot(t)*HSs,
                     smem, bias_r, creg, U0, wv, lane, tid);
    } else if (type == 2) {
      layer_phase<2>(h2r + slot(t)*HSs,
                     h3r + slot(t-1)*HBs,
                     h3r + slot(t)*HBs,
                     smem, bias_r, creg, U0, wv, lane, tid);
    } else {
      // ---- linear head step t: per WG m128 x n16, 8 waves x 16 rows ----
      const unsigned short* hA = h3r + slot(t)*HBs;
      const size_t lof = (size_t)(lane >> 4)*128 + (size_t)l15*8;
      const unsigned short* pa0 = hA + (size_t)wv*512 + lof;
      const int rowbyte = l15*2048;
      const int xr = (l15 & 7) << 4;
      const int klobyte = ((lane >> 4) << 3)*2;
      floatx4 oacc;
      { floatx4 b4 = {bias_r[0], bias_r[0], bias_r[0], bias_r[0]}; oacc = b4; }
      short8 A0[4], A1[4];
      auto HLOAD = [&](int c, short8 (&A)[4]) {
        #pragma unroll
        for (int ks = 0; ks < 4; ++ks)
          A[ks] = *(const short8*)(pa0 + (size_t)(c*4 + ks)*4096);
      };
      auto HMM = [&](int c, short8 (&A)[4]) {
        #pragma unroll
        for (int ks = 0; ks < 4; ++ks) {
          const int kb = c*128 + ks*32;
          short8 bw = *(const short8*)(smem + rowbyte + ((kb*2 + klobyte) ^ xr));
          oacc = __builtin_amdgcn_mfma_f32_16x16x32_bf16(A[ks], bw, oacc, 0, 0, 0);
        }
      };
      HLOAD(0, A0);
      #pragma unroll 1
      for (int ch = 0; ch < 8; ch += 2) {
        HLOAD(ch + 1, A1);
        HMM(ch, A0);
        if (ch + 2 < 8) HLOAD(ch + 2, A0);
        HMM(ch + 1, A1);
      }
      const int col = osec + l15;
      const int b0 = wv*16 + ((lane >> 4) << 2);
      #pragma unroll
      for (int j = 0; j < 4; ++j)
        st_dword_cg(out + ((size_t)t*Bb + b0 + j)*Dl + col,
                    __float_as_uint(oacc[j]));
    }

    // ---- completion publish + periodic local cache invalidate ----
    waitcnt_vm0();
    __syncthreads();
    if (tid == 0) st_dword_cg(flags + wg, (unsigned)(t + 1));
    if ((t & 7) == 7)
      __builtin_amdgcn_fence(__ATOMIC_ACQUIRE, "agent");
  }
}

extern "C" void kernel_launch(void* const* d_in, const int* in_sizes, int n_in,
                              void* d_out, int out_size, void* d_ws, size_t ws_size,
                              hipStream_t stream)
{
  if (ws_size < WS_NEED) return;

  const float* X    = (const float*)d_in[0];
  const float* Wih1 = (const float*)d_in[1];
  const float* Whh1 = (const float*)d_in[2];
  const float* bih1 = (const float*)d_in[3];
  const float* bhh1 = (const float*)d_in[4];
  const float* Wih2 = (const float*)d_in[5];
  const float* Whh2 = (const float*)d_in[6];
  const float* bih2 = (const float*)d_in[7];
  const float* bhh2 = (const float*)d_in[8];
  const float* Wih3 = (const float*)d_in[9];
  const float* Whh3 = (const float*)d_in[10];
  const float* bih3 = (const float*)d_in[11];
  const float* bhh3 = (const float*)d_in[12];
  const float* Wlin = (const float*)d_in[13];
  const float* blin = (const float*)d_in[14];
  unsigned char* ws = (unsigned char*)d_ws;

  lstm_init<<<2048, 256, 0, stream>>>(X, Wih1, Whh1, bih1, bhh1,
                                      Wih2, Whh2, bih2, bhh2,
                                      Wih3, Whh3, bih3, bhh3,
                                      Wlin, blin, ws);
  lstm_persist<<<NWG, 512, SMEM_BYTES, stream>>>((float*)d_out, ws);
}